// Round 3
// baseline (783.529 us; speedup 1.0000x reference)
//
#include <hip/hip_runtime.h>
#include <math.h>

#define NOBS 1024
#define NX   128
#define NY   256
#define NIT  200
#define ROWS 2                      // rows per FISTA block
#define NBLK (NOBS / ROWS)          // 512 blocks -> 2 blocks/CU

typedef _Float16 f16x8 __attribute__((ext_vector_type(8)));
typedef _Float16 f16x4 __attribute__((ext_vector_type(4)));
typedef float    f32x4 __attribute__((ext_vector_type(4)));

// ---------------------------------------------------------------------------
// K1: Y_hat = X @ W^T + b      grid=(NOBS), block=256 (thread j -> column j)
// ---------------------------------------------------------------------------
__global__ __launch_bounds__(256) void yhat_kernel(const float* __restrict__ X,
                                                   const float* __restrict__ W,
                                                   const float* __restrict__ b,
                                                   float* __restrict__ yhat) {
    __shared__ float xs[NX];
    const int i = blockIdx.x;
    const int j = threadIdx.x;
    if (j < NX) xs[j] = X[i * NX + j];
    __syncthreads();
    const float4* wr = reinterpret_cast<const float4*>(W + j * NX);
    const float4* xr = reinterpret_cast<const float4*>(xs);
    float acc = b[j];
#pragma unroll
    for (int k = 0; k < NX / 4; ++k) {
        float4 w4 = wr[k];
        float4 x4 = xr[k];
        acc += w4.x * x4.x + w4.y * x4.y + w4.z * x4.z + w4.w * x4.w;
    }
    yhat[i * NY + j] = acc;
}

// ---------------------------------------------------------------------------
// K2: mu[a] = mean_i (Y - Y_hat)[i][a]      grid=(NY), block=256
// ---------------------------------------------------------------------------
__global__ __launch_bounds__(256) void mu_kernel(const float* __restrict__ Y,
                                                 const float* __restrict__ yhat,
                                                 float* __restrict__ mu) {
    const int a = blockIdx.x;
    const int t = threadIdx.x;
    float s = 0.f;
    for (int i = t; i < NOBS; i += 256)
        s += Y[i * NY + a] - yhat[i * NY + a];
#pragma unroll
    for (int off = 32; off; off >>= 1) s += __shfl_xor(s, off);
    __shared__ float red[4];
    if ((t & 63) == 0) red[t >> 6] = s;
    __syncthreads();
    if (t == 0) mu[a] = (red[0] + red[1] + red[2] + red[3]) * (1.0f / NOBS);
}

// ---------------------------------------------------------------------------
// K3: Sigma[a][j] = (1/NOBS) * sum_i epc[i][a]*epc[i][j]   grid=(NY), block=256
// ---------------------------------------------------------------------------
__global__ __launch_bounds__(256) void sigma_kernel(const float* __restrict__ Y,
                                                    const float* __restrict__ yhat,
                                                    const float* __restrict__ mu,
                                                    float* __restrict__ Sigma) {
    const int a = blockIdx.x;
    const int j = threadIdx.x;
    __shared__ float ca[NOBS];
    const float mua = mu[a];
    for (int i = j; i < NOBS; i += 256)
        ca[i] = Y[i * NY + a] - yhat[i * NY + a] - mua;
    __syncthreads();
    const float muj = mu[j];
    float s = 0.f;
#pragma unroll 4
    for (int i = 0; i < NOBS; ++i) {
        float cj = Y[i * NY + j] - yhat[i * NY + j] - muj;
        s += ca[i] * cj;
    }
    Sigma[a * NY + j] = s * (1.0f / NOBS);
}

// ---------------------------------------------------------------------------
// K4: step = 1 / (2*||Sigma||_F + 1e-8)      grid=(1), block=1024
// ---------------------------------------------------------------------------
__global__ __launch_bounds__(1024) void step_kernel(const float* __restrict__ Sigma,
                                                    float* __restrict__ stepv) {
    const int t = threadIdx.x;
    float s = 0.f;
    for (int idx = t; idx < NY * NY; idx += 1024) {
        float v = Sigma[idx];
        s += v * v;
    }
#pragma unroll
    for (int off = 32; off; off >>= 1) s += __shfl_xor(s, off);
    __shared__ float red[16];
    if ((t & 63) == 0) red[t >> 6] = s;
    __syncthreads();
    if (t < 16) {
        float v = red[t];
#pragma unroll
        for (int off = 8; off; off >>= 1) v += __shfl_xor(v, off);
        if (t == 0) stepv[0] = 1.0f / (2.0f * sqrtf(v) + 1e-8f);
    }
}

// ---------------------------------------------------------------------------
// K5: persistent FISTA via MFMA. grid=(NBLK) blocks, 256 threads (4 waves).
// Block owns ROWS=2 rows -> 2 blocks/CU -> 2 waves/SIMD for latency hiding.
// Wave w owns output columns [64w, 64w+64) for the grad GEMM (B-slice of
// Sigma in f16 registers). Wave w projects row (w&1); waves 2,3 duplicate
// rows 0,1 bit-identically (keeps SIMDs symmetric; benign same-value race).
// ---------------------------------------------------------------------------
__global__ __launch_bounds__(256, 1) void fista_mfma_kernel(
        const float* __restrict__ Sigma,
        const float* __restrict__ yhat,
        const float* __restrict__ stepv,
        float* __restrict__ zout) {
    __shared__ _Float16 zyA[16 * 256];   // A matrix, swizzled: byte ^= (row&7)<<4
    __shared__ float    vbuf[ROWS * 256]; // fp32 zy / v scratch

    const int tid  = threadIdx.x;
    const int w    = tid >> 6;           // wave id = column-slice id
    const int lane = tid & 63;
    const int r0   = blockIdx.x * ROWS;
    const int prow = w & (ROWS - 1);     // row this wave projects

    const float st  = stepv[0];
    const float st2 = 2.0f * st;

    // ---- init LDS ----
    {
        f16x8 zv = {0, 0, 0, 0, 0, 0, 0, 0};
        for (int i = tid; i < 16 * 256 / 8; i += 256)
            *reinterpret_cast<f16x8*>(zyA + i * 8) = zv;
    }
    __syncthreads();
    {
        const _Float16 u = (_Float16)(1.0f / 256.0f);
        for (int i = tid; i < ROWS * 256; i += 256) {  // rows 0..ROWS-1 (uniform
            zyA[i]  = u;                               //  fill: swizzle-invariant)
            vbuf[i] = 1.0f / 256.0f;
        }
    }

    // ---- preload B fragments: B[k][col] = Sigma[col][k] (symmetry) ----
    const int colg = w * 64 + (lane & 15);
    const int ksub = (lane >> 4) * 8;
    f16x8 bfr[4][8];
#pragma unroll
    for (int n = 0; n < 4; ++n) {
#pragma unroll
        for (int kk = 0; kk < 8; ++kk) {
            const float* p = Sigma + (colg + n * 16) * NY + kk * 32 + ksub;
            float4 lo = *reinterpret_cast<const float4*>(p);
            float4 hi = *reinterpret_cast<const float4*>(p + 4);
            f16x8 bv;
            bv[0] = (_Float16)lo.x; bv[1] = (_Float16)lo.y;
            bv[2] = (_Float16)lo.z; bv[3] = (_Float16)lo.w;
            bv[4] = (_Float16)hi.x; bv[5] = (_Float16)hi.y;
            bv[6] = (_Float16)hi.z; bv[7] = (_Float16)hi.w;
            bfr[n][kk] = bv;
        }
    }

    // ---- preload st * yhat for the epilogue (lanes 0..15 only) ----
    float styh[4 * ROWS];
    if (lane < 16) {
#pragma unroll
        for (int r = 0; r < ROWS; ++r)
#pragma unroll
            for (int n = 0; n < 4; ++n)
                styh[r * 4 + n] = st * yhat[(r0 + r) * NY + w * 64 + n * 16 + lane];
    }

    f32x4 zz = {1.0f / 256.0f, 1.0f / 256.0f, 1.0f / 256.0f, 1.0f / 256.0f};
    float tk = 1.0f;
    float th = 0.0f;                      // warm-started simplex threshold
    __syncthreads();

    for (int it = 0; it < NIT; ++it) {
        // ---- grad phase: acc[n] = (Zy @ Sigma) tile (16x16), K=256 ----
        f32x4 acc[4] = {{0,0,0,0},{0,0,0,0},{0,0,0,0},{0,0,0,0}};
        const int arow  = lane & 15;
        const int abase = arow * 512;
        const int aswz  = (arow & 7) << 4;
#pragma unroll
        for (int kk = 0; kk < 8; ++kk) {
            const int aoff = (kk * 64 + (lane >> 4) * 16) ^ aswz;
            f16x8 af = *reinterpret_cast<const f16x8*>(
                reinterpret_cast<const char*>(zyA) + abase + aoff);
#pragma unroll
            for (int n = 0; n < 4; ++n)
                acc[n] = __builtin_amdgcn_mfma_f32_16x16x32_f16(af, bfr[n][kk],
                                                                acc[n], 0, 0, 0);
        }
        // ---- epilogue: v = zy - st*(2g - yhat); lanes 0..15 hold rows ----
        if (lane < 16) {
#pragma unroll
            for (int r = 0; r < ROWS; ++r) {
#pragma unroll
                for (int n = 0; n < 4; ++n) {
                    const int c = w * 64 + n * 16 + lane;
                    float zyo = vbuf[r * 256 + c];
                    vbuf[r * 256 + c] = zyo - st2 * acc[n][r] + styh[r * 4 + n];
                }
            }
        }
        __syncthreads();

        // ---- projection: wave w projects row prow onto the simplex ----
        f32x4 v4 = *reinterpret_cast<const f32x4*>(vbuf + prow * 256 + lane * 4);
        float ps = v4[0] + v4[1] + v4[2] + v4[3];
#pragma unroll
        for (int off = 32; off; off >>= 1) ps += __shfl_xor(ps, off);
        const float th0 = (ps - 1.0f) * (1.0f / 256.0f);   // always <= theta*

        for (int nit = 0; nit < 16; ++nit) {
            float s = 0.f, c = 0.f, d;
            d = v4[0] - th; if (d > 0.f) { s += d; c += 1.f; }
            d = v4[1] - th; if (d > 0.f) { s += d; c += 1.f; }
            d = v4[2] - th; if (d > 0.f) { s += d; c += 1.f; }
            d = v4[3] - th; if (d > 0.f) { s += d; c += 1.f; }
#pragma unroll
            for (int off = 32; off; off >>= 1) {
                s += __shfl_xor(s, off);
                c += __shfl_xor(c, off);
            }
            if (c < 0.5f) { th = th0; continue; }   // overshot support: restart low
            if (fabsf(s - 1.0f) <= 1e-6f) break;    // converged (exact segment)
            th += (s - 1.0f) / c;                   // Newton (finite convergence)
        }

        f32x4 zn;
        zn[0] = fmaxf(v4[0] - th, 0.f);
        zn[1] = fmaxf(v4[1] - th, 0.f);
        zn[2] = fmaxf(v4[2] - th, 0.f);
        zn[3] = fmaxf(v4[3] - th, 0.f);

        const float tn   = 0.5f * (1.0f + sqrtf(1.0f + 4.0f * tk * tk));
        const float beta = (tk - 1.0f) / tn;
        tk = tn;
        f32x4 zyn;
        zyn[0] = zn[0] + beta * (zn[0] - zz[0]);
        zyn[1] = zn[1] + beta * (zn[1] - zz[1]);
        zyn[2] = zn[2] + beta * (zn[2] - zz[2]);
        zyn[3] = zn[3] + beta * (zn[3] - zz[3]);
        zz = zn;

        // write zyn: fp32 -> vbuf, f16 -> zyA (swizzled row prow)
        // waves with the same prow write identical bits (benign race)
        *reinterpret_cast<f32x4*>(vbuf + prow * 256 + lane * 4) = zyn;
        {
            const int off = (lane * 8) ^ ((prow & 7) << 4);
            f16x4 hz;
            hz[0] = (_Float16)zyn[0]; hz[1] = (_Float16)zyn[1];
            hz[2] = (_Float16)zyn[2]; hz[3] = (_Float16)zyn[3];
            *reinterpret_cast<f16x4*>(
                reinterpret_cast<char*>(zyA) + prow * 512 + off) = hz;
        }
        __syncthreads();
    }

    // ---- output: waves 0..ROWS-1 write their rows ----
    if (w < ROWS)
        *reinterpret_cast<f32x4*>(zout + (r0 + w) * NY + lane * 4) = zz;
}

// ---------------------------------------------------------------------------
extern "C" void kernel_launch(void* const* d_in, const int* in_sizes, int n_in,
                              void* d_out, int out_size, void* d_ws, size_t ws_size,
                              hipStream_t stream) {
    const float* X = (const float*)d_in[0];
    const float* Y = (const float*)d_in[1];
    const float* W = (const float*)d_in[2];
    const float* b = (const float*)d_in[3];

    float* z_out = (float*)d_out;            // (1024, 256)
    float* yhat  = z_out + NOBS * NY;        // (1024, 256) -- second output

    float* ws    = (float*)d_ws;
    float* mu    = ws;                       // 256
    float* Sigma = ws + NY;                  // 65536
    float* stepv = ws + NY + NY * NY;        // 1

    yhat_kernel<<<NOBS, 256, 0, stream>>>(X, W, b, yhat);
    mu_kernel<<<NY, 256, 0, stream>>>(Y, yhat, mu);
    sigma_kernel<<<NY, 256, 0, stream>>>(Y, yhat, mu, Sigma);
    step_kernel<<<1, 1024, 0, stream>>>(Sigma, stepv);
    fista_mfma_kernel<<<NBLK, 256, 0, stream>>>(Sigma, yhat, stepv, z_out);
}

// Round 4
// 356.448 us; speedup vs baseline: 2.1982x; 2.1982x over previous
//
#include <hip/hip_runtime.h>
#include <math.h>

#define NOBS 1024
#define NX   128
#define NY   256
#define NIT  200
#define ROWS 4                      // rows per FISTA block
#define NBLK (NOBS / ROWS)          // 256 blocks = 1/CU; chain-bound, not occ-bound

typedef _Float16 f16x8 __attribute__((ext_vector_type(8)));
typedef _Float16 f16x4 __attribute__((ext_vector_type(4)));
typedef float    f32x4 __attribute__((ext_vector_type(4)));

// ---- fast 64-lane sum: 6 DPP adds, total lands in lane 63, readlane -> SGPR
template <int CTRL>
__device__ __forceinline__ float dpp_add(float x) {
    int yi = __builtin_amdgcn_update_dpp(0, __builtin_bit_cast(int, x),
                                         CTRL, 0xF, 0xF, true);
    return x + __builtin_bit_cast(float, yi);
}
__device__ __forceinline__ float dpp_sum64(float x) {
    x = dpp_add<0x111>(x);   // row_shr:1
    x = dpp_add<0x112>(x);   // row_shr:2
    x = dpp_add<0x114>(x);   // row_shr:4
    x = dpp_add<0x118>(x);   // row_shr:8
    x = dpp_add<0x142>(x);   // row_bcast:15
    x = dpp_add<0x143>(x);   // row_bcast:31
    return __builtin_bit_cast(float,
        __builtin_amdgcn_readlane(__builtin_bit_cast(int, x), 63));
}

// ---------------------------------------------------------------------------
// K1: Y_hat = X @ W^T + b      grid=(NOBS), block=256 (thread j -> column j)
// ---------------------------------------------------------------------------
__global__ __launch_bounds__(256) void yhat_kernel(const float* __restrict__ X,
                                                   const float* __restrict__ W,
                                                   const float* __restrict__ b,
                                                   float* __restrict__ yhat) {
    __shared__ float xs[NX];
    const int i = blockIdx.x;
    const int j = threadIdx.x;
    if (j < NX) xs[j] = X[i * NX + j];
    __syncthreads();
    const float4* wr = reinterpret_cast<const float4*>(W + j * NX);
    const float4* xr = reinterpret_cast<const float4*>(xs);
    float acc = b[j];
#pragma unroll
    for (int k = 0; k < NX / 4; ++k) {
        float4 w4 = wr[k];
        float4 x4 = xr[k];
        acc += w4.x * x4.x + w4.y * x4.y + w4.z * x4.z + w4.w * x4.w;
    }
    yhat[i * NY + j] = acc;
}

// ---------------------------------------------------------------------------
// K2: mu[a] = mean_i (Y - Y_hat)[i][a]      grid=(NY), block=256
// ---------------------------------------------------------------------------
__global__ __launch_bounds__(256) void mu_kernel(const float* __restrict__ Y,
                                                 const float* __restrict__ yhat,
                                                 float* __restrict__ mu) {
    const int a = blockIdx.x;
    const int t = threadIdx.x;
    float s = 0.f;
    for (int i = t; i < NOBS; i += 256)
        s += Y[i * NY + a] - yhat[i * NY + a];
#pragma unroll
    for (int off = 32; off; off >>= 1) s += __shfl_xor(s, off);
    __shared__ float red[4];
    if ((t & 63) == 0) red[t >> 6] = s;
    __syncthreads();
    if (t == 0) mu[a] = (red[0] + red[1] + red[2] + red[3]) * (1.0f / NOBS);
}

// ---------------------------------------------------------------------------
// K3: Sigma[a][j] = (1/NOBS) * sum_i epc[i][a]*epc[i][j]   grid=(NY), block=256
// ---------------------------------------------------------------------------
__global__ __launch_bounds__(256) void sigma_kernel(const float* __restrict__ Y,
                                                    const float* __restrict__ yhat,
                                                    const float* __restrict__ mu,
                                                    float* __restrict__ Sigma) {
    const int a = blockIdx.x;
    const int j = threadIdx.x;
    __shared__ float ca[NOBS];
    const float mua = mu[a];
    for (int i = j; i < NOBS; i += 256)
        ca[i] = Y[i * NY + a] - yhat[i * NY + a] - mua;
    __syncthreads();
    const float muj = mu[j];
    float s = 0.f;
#pragma unroll 4
    for (int i = 0; i < NOBS; ++i) {
        float cj = Y[i * NY + j] - yhat[i * NY + j] - muj;
        s += ca[i] * cj;
    }
    Sigma[a * NY + j] = s * (1.0f / NOBS);
}

// ---------------------------------------------------------------------------
// K4: step = 1 / (2*||Sigma||_F + 1e-8)      grid=(1), block=1024
// ---------------------------------------------------------------------------
__global__ __launch_bounds__(1024) void step_kernel(const float* __restrict__ Sigma,
                                                    float* __restrict__ stepv) {
    const int t = threadIdx.x;
    float s = 0.f;
    for (int idx = t; idx < NY * NY; idx += 1024) {
        float v = Sigma[idx];
        s += v * v;
    }
#pragma unroll
    for (int off = 32; off; off >>= 1) s += __shfl_xor(s, off);
    __shared__ float red[16];
    if ((t & 63) == 0) red[t >> 6] = s;
    __syncthreads();
    if (t < 16) {
        float v = red[t];
#pragma unroll
        for (int off = 8; off; off >>= 1) v += __shfl_xor(v, off);
        if (t == 0) stepv[0] = 1.0f / (2.0f * sqrtf(v) + 1e-8f);
    }
}

// ---------------------------------------------------------------------------
// K5: persistent FISTA via MFMA. grid=(NBLK) blocks, 256 threads (4 waves).
// Block owns 4 rows. Wave w owns output columns [64w, 64w+64) for the grad
// GEMM (B-slice of Sigma in f16 registers) and projects row w. Projection
// reductions use DPP adds + ballot/popc (no ds_swizzle shuffles).
// ---------------------------------------------------------------------------
__global__ __launch_bounds__(256, 1) void fista_mfma_kernel(
        const float* __restrict__ Sigma,
        const float* __restrict__ yhat,
        const float* __restrict__ stepv,
        float* __restrict__ zout) {
    __shared__ _Float16 zyA[16 * 256];   // A matrix, swizzled: byte ^= (row&7)<<4
    __shared__ float    vbuf[ROWS * 256]; // fp32 zy / v scratch

    const int tid  = threadIdx.x;
    const int w    = tid >> 6;           // wave id = column-slice id = row id
    const int lane = tid & 63;
    const int r0   = blockIdx.x * ROWS;

    const float st  = stepv[0];
    const float st2 = 2.0f * st;

    // ---- init LDS ----
    {
        f16x8 zv = {0, 0, 0, 0, 0, 0, 0, 0};
        for (int i = tid; i < 16 * 256 / 8; i += 256)
            *reinterpret_cast<f16x8*>(zyA + i * 8) = zv;
    }
    __syncthreads();
    {
        const _Float16 u = (_Float16)(1.0f / 256.0f);
        for (int i = tid; i < ROWS * 256; i += 256) {  // rows 0..ROWS-1 (uniform
            zyA[i]  = u;                               //  fill: swizzle-invariant)
            vbuf[i] = 1.0f / 256.0f;
        }
    }

    // ---- preload B fragments: B[k][col] = Sigma[col][k] (symmetry) ----
    const int colg = w * 64 + (lane & 15);
    const int ksub = (lane >> 4) * 8;
    f16x8 bfr[4][8];
#pragma unroll
    for (int n = 0; n < 4; ++n) {
#pragma unroll
        for (int kk = 0; kk < 8; ++kk) {
            const float* p = Sigma + (colg + n * 16) * NY + kk * 32 + ksub;
            float4 lo = *reinterpret_cast<const float4*>(p);
            float4 hi = *reinterpret_cast<const float4*>(p + 4);
            f16x8 bv;
            bv[0] = (_Float16)lo.x; bv[1] = (_Float16)lo.y;
            bv[2] = (_Float16)lo.z; bv[3] = (_Float16)lo.w;
            bv[4] = (_Float16)hi.x; bv[5] = (_Float16)hi.y;
            bv[6] = (_Float16)hi.z; bv[7] = (_Float16)hi.w;
            bfr[n][kk] = bv;
        }
    }

    // ---- preload st * yhat for the epilogue (lanes 0..15 only) ----
    float styh[4 * ROWS];
    if (lane < 16) {
#pragma unroll
        for (int r = 0; r < ROWS; ++r)
#pragma unroll
            for (int n = 0; n < 4; ++n)
                styh[r * 4 + n] = st * yhat[(r0 + r) * NY + w * 64 + n * 16 + lane];
    }

    f32x4 zz = {1.0f / 256.0f, 1.0f / 256.0f, 1.0f / 256.0f, 1.0f / 256.0f};
    float tk = 1.0f;
    float th = 0.0f;                      // warm-started simplex threshold
    __syncthreads();

    for (int it = 0; it < NIT; ++it) {
        // ---- grad phase: acc[n] = (Zy @ Sigma) tile (16x16), K=256 ----
        f32x4 acc[4] = {{0,0,0,0},{0,0,0,0},{0,0,0,0},{0,0,0,0}};
        const int arow  = lane & 15;
        const int abase = arow * 512;
        const int aswz  = (arow & 7) << 4;
#pragma unroll
        for (int kk = 0; kk < 8; ++kk) {
            const int aoff = (kk * 64 + (lane >> 4) * 16) ^ aswz;
            f16x8 af = *reinterpret_cast<const f16x8*>(
                reinterpret_cast<const char*>(zyA) + abase + aoff);
#pragma unroll
            for (int n = 0; n < 4; ++n)
                acc[n] = __builtin_amdgcn_mfma_f32_16x16x32_f16(af, bfr[n][kk],
                                                                acc[n], 0, 0, 0);
        }
        // ---- epilogue: v = zy - st*(2g - yhat); lanes 0..15 hold rows ----
        if (lane < 16) {
#pragma unroll
            for (int r = 0; r < ROWS; ++r) {
#pragma unroll
                for (int n = 0; n < 4; ++n) {
                    const int c = w * 64 + n * 16 + lane;
                    float zyo = vbuf[r * 256 + c];
                    vbuf[r * 256 + c] = zyo - st2 * acc[n][r] + styh[r * 4 + n];
                }
            }
        }
        __syncthreads();

        // ---- projection: wave w projects row w onto the simplex ----
        f32x4 v4 = *reinterpret_cast<const f32x4*>(vbuf + w * 256 + lane * 4);
        const float ps  = dpp_sum64(v4[0] + v4[1] + v4[2] + v4[3]);
        const float th0 = (ps - 1.0f) * (1.0f / 256.0f);   // always <= theta*

        for (int nit = 0; nit < 16; ++nit) {
            float d0 = v4[0] - th, d1 = v4[1] - th;
            float d2 = v4[2] - th, d3 = v4[3] - th;
            float sp = fmaxf(d0, 0.f) + fmaxf(d1, 0.f) +
                       fmaxf(d2, 0.f) + fmaxf(d3, 0.f);
            float s_tot = dpp_sum64(sp);                    // uniform (SGPR)
            int ci = __popcll(__ballot(d0 > 0.f)) + __popcll(__ballot(d1 > 0.f)) +
                     __popcll(__ballot(d2 > 0.f)) + __popcll(__ballot(d3 > 0.f));
            if (ci == 0) { th = th0; continue; }            // overshot: restart low
            if (fabsf(s_tot - 1.0f) <= 1e-6f) break;        // converged
            th += (s_tot - 1.0f) / (float)ci;               // Newton step
        }

        f32x4 zn;
        zn[0] = fmaxf(v4[0] - th, 0.f);
        zn[1] = fmaxf(v4[1] - th, 0.f);
        zn[2] = fmaxf(v4[2] - th, 0.f);
        zn[3] = fmaxf(v4[3] - th, 0.f);

        const float tn   = 0.5f * (1.0f + sqrtf(1.0f + 4.0f * tk * tk));
        const float beta = (tk - 1.0f) / tn;
        tk = tn;
        f32x4 zyn;
        zyn[0] = zn[0] + beta * (zn[0] - zz[0]);
        zyn[1] = zn[1] + beta * (zn[1] - zz[1]);
        zyn[2] = zn[2] + beta * (zn[2] - zz[2]);
        zyn[3] = zn[3] + beta * (zn[3] - zz[3]);
        zz = zn;

        // write zyn: fp32 -> vbuf, f16 -> zyA (swizzled row w)
        *reinterpret_cast<f32x4*>(vbuf + w * 256 + lane * 4) = zyn;
        {
            const int off = (lane * 8) ^ ((w & 7) << 4);
            f16x4 hz;
            hz[0] = (_Float16)zyn[0]; hz[1] = (_Float16)zyn[1];
            hz[2] = (_Float16)zyn[2]; hz[3] = (_Float16)zyn[3];
            *reinterpret_cast<f16x4*>(
                reinterpret_cast<char*>(zyA) + w * 512 + off) = hz;
        }
        __syncthreads();
    }

    // ---- output: zz of wave w is row r0+w ----
    *reinterpret_cast<f32x4*>(zout + (r0 + w) * NY + lane * 4) = zz;
}

// ---------------------------------------------------------------------------
extern "C" void kernel_launch(void* const* d_in, const int* in_sizes, int n_in,
                              void* d_out, int out_size, void* d_ws, size_t ws_size,
                              hipStream_t stream) {
    const float* X = (const float*)d_in[0];
    const float* Y = (const float*)d_in[1];
    const float* W = (const float*)d_in[2];
    const float* b = (const float*)d_in[3];

    float* z_out = (float*)d_out;            // (1024, 256)
    float* yhat  = z_out + NOBS * NY;        // (1024, 256) -- second output

    float* ws    = (float*)d_ws;
    float* mu    = ws;                       // 256
    float* Sigma = ws + NY;                  // 65536
    float* stepv = ws + NY + NY * NY;        // 1

    yhat_kernel<<<NOBS, 256, 0, stream>>>(X, W, b, yhat);
    mu_kernel<<<NY, 256, 0, stream>>>(Y, yhat, mu);
    sigma_kernel<<<NY, 256, 0, stream>>>(Y, yhat, mu, Sigma);
    step_kernel<<<1, 1024, 0, stream>>>(Sigma, stepv);
    fista_mfma_kernel<<<NBLK, 256, 0, stream>>>(Sigma, yhat, stepv, z_out);
}

// Round 5
// 346.155 us; speedup vs baseline: 2.2635x; 1.0297x over previous
//
#include <hip/hip_runtime.h>
#include <math.h>

#define NOBS 1024
#define NX   128
#define NY   256
#define NIT  200
#define ROWS 2                      // rows per FISTA block
#define NBLK (NOBS / ROWS)          // 512 blocks -> 2 blocks/CU co-resident

typedef _Float16 f16x8 __attribute__((ext_vector_type(8)));
typedef _Float16 f16x4 __attribute__((ext_vector_type(4)));
typedef float    f32x4 __attribute__((ext_vector_type(4)));

// ---- fast 64-lane sum: 6 DPP adds, total lands in lane 63, readlane -> SGPR
template <int CTRL>
__device__ __forceinline__ float dpp_add(float x) {
    int yi = __builtin_amdgcn_update_dpp(0, __builtin_bit_cast(int, x),
                                         CTRL, 0xF, 0xF, true);
    return x + __builtin_bit_cast(float, yi);
}
__device__ __forceinline__ float dpp_sum64(float x) {
    x = dpp_add<0x111>(x);   // row_shr:1
    x = dpp_add<0x112>(x);   // row_shr:2
    x = dpp_add<0x114>(x);   // row_shr:4
    x = dpp_add<0x118>(x);   // row_shr:8
    x = dpp_add<0x142>(x);   // row_bcast:15
    x = dpp_add<0x143>(x);   // row_bcast:31
    return __builtin_bit_cast(float,
        __builtin_amdgcn_readlane(__builtin_bit_cast(int, x), 63));
}

// ---------------------------------------------------------------------------
// K1: Y_hat = X @ W^T + b      grid=(NOBS), block=256 (thread j -> column j)
// ---------------------------------------------------------------------------
__global__ __launch_bounds__(256) void yhat_kernel(const float* __restrict__ X,
                                                   const float* __restrict__ W,
                                                   const float* __restrict__ b,
                                                   float* __restrict__ yhat) {
    __shared__ float xs[NX];
    const int i = blockIdx.x;
    const int j = threadIdx.x;
    if (j < NX) xs[j] = X[i * NX + j];
    __syncthreads();
    const float4* wr = reinterpret_cast<const float4*>(W + j * NX);
    const float4* xr = reinterpret_cast<const float4*>(xs);
    float acc = b[j];
#pragma unroll
    for (int k = 0; k < NX / 4; ++k) {
        float4 w4 = wr[k];
        float4 x4 = xr[k];
        acc += w4.x * x4.x + w4.y * x4.y + w4.z * x4.z + w4.w * x4.w;
    }
    yhat[i * NY + j] = acc;
}

// ---------------------------------------------------------------------------
// K2: mu[a] = mean_i (Y - Y_hat)[i][a]      grid=(NY), block=256
// ---------------------------------------------------------------------------
__global__ __launch_bounds__(256) void mu_kernel(const float* __restrict__ Y,
                                                 const float* __restrict__ yhat,
                                                 float* __restrict__ mu) {
    const int a = blockIdx.x;
    const int t = threadIdx.x;
    float s = 0.f;
    for (int i = t; i < NOBS; i += 256)
        s += Y[i * NY + a] - yhat[i * NY + a];
#pragma unroll
    for (int off = 32; off; off >>= 1) s += __shfl_xor(s, off);
    __shared__ float red[4];
    if ((t & 63) == 0) red[t >> 6] = s;
    __syncthreads();
    if (t == 0) mu[a] = (red[0] + red[1] + red[2] + red[3]) * (1.0f / NOBS);
}

// ---------------------------------------------------------------------------
// K3: Sigma[a][j] = (1/NOBS) * sum_i epc[i][a]*epc[i][j]   grid=(NY), block=256
// ---------------------------------------------------------------------------
__global__ __launch_bounds__(256) void sigma_kernel(const float* __restrict__ Y,
                                                    const float* __restrict__ yhat,
                                                    const float* __restrict__ mu,
                                                    float* __restrict__ Sigma) {
    const int a = blockIdx.x;
    const int j = threadIdx.x;
    __shared__ float ca[NOBS];
    const float mua = mu[a];
    for (int i = j; i < NOBS; i += 256)
        ca[i] = Y[i * NY + a] - yhat[i * NY + a] - mua;
    __syncthreads();
    const float muj = mu[j];
    float s = 0.f;
#pragma unroll 4
    for (int i = 0; i < NOBS; ++i) {
        float cj = Y[i * NY + j] - yhat[i * NY + j] - muj;
        s += ca[i] * cj;
    }
    Sigma[a * NY + j] = s * (1.0f / NOBS);
}

// ---------------------------------------------------------------------------
// K4: step = 1 / (2*||Sigma||_F + 1e-8)      grid=(1), block=1024
// ---------------------------------------------------------------------------
__global__ __launch_bounds__(1024) void step_kernel(const float* __restrict__ Sigma,
                                                    float* __restrict__ stepv) {
    const int t = threadIdx.x;
    float s = 0.f;
    for (int idx = t; idx < NY * NY; idx += 1024) {
        float v = Sigma[idx];
        s += v * v;
    }
#pragma unroll
    for (int off = 32; off; off >>= 1) s += __shfl_xor(s, off);
    __shared__ float red[16];
    if ((t & 63) == 0) red[t >> 6] = s;
    __syncthreads();
    if (t < 16) {
        float v = red[t];
#pragma unroll
        for (int off = 8; off; off >>= 1) v += __shfl_xor(v, off);
        if (t == 0) stepv[0] = 1.0f / (2.0f * sqrtf(v) + 1e-8f);
    }
}

// ---------------------------------------------------------------------------
// K5: persistent FISTA via MFMA. grid=(NBLK) blocks, 256 threads (4 waves).
// Block owns ROWS=2 rows; launch_bounds(256,2) forces total regs <= 256 so
// 2 blocks/CU truly co-reside (round-3 failure was AGPR-side overflow).
// Wave w owns output columns [64w, 64w+64) (B-slice of Sigma in f16 regs);
// wave w projects row (w&1), waves 2,3 duplicate bit-identically.
// ---------------------------------------------------------------------------
__global__ __launch_bounds__(256, 2) void fista_mfma_kernel(
        const float* __restrict__ Sigma,
        const float* __restrict__ yhat,
        const float* __restrict__ stepv,
        float* __restrict__ zout) {
    __shared__ _Float16 zyA[16 * 256];    // A matrix, swizzled: byte ^= (row&7)<<4
    __shared__ float    vbuf[ROWS * 256]; // fp32 zy / v scratch

    const int tid  = threadIdx.x;
    const int w    = tid >> 6;           // wave id = column-slice id
    const int lane = tid & 63;
    const int r0   = blockIdx.x * ROWS;
    const int prow = w & (ROWS - 1);     // row this wave projects

    const float st  = stepv[0];
    const float st2 = 2.0f * st;

    // ---- init LDS ----
    {
        f16x8 zv = {0, 0, 0, 0, 0, 0, 0, 0};
        for (int i = tid; i < 16 * 256 / 8; i += 256)
            *reinterpret_cast<f16x8*>(zyA + i * 8) = zv;
    }
    __syncthreads();
    {
        const _Float16 u = (_Float16)(1.0f / 256.0f);
        for (int i = tid; i < ROWS * 256; i += 256) {  // rows 0..ROWS-1 (uniform
            zyA[i]  = u;                               //  fill: swizzle-invariant)
            vbuf[i] = 1.0f / 256.0f;
        }
    }

    // ---- preload B fragments: B[k][col] = Sigma[col][k] (symmetry) ----
    const int colg = w * 64 + (lane & 15);
    const int ksub = (lane >> 4) * 8;
    f16x8 bfr[4][8];
#pragma unroll
    for (int n = 0; n < 4; ++n) {
#pragma unroll
        for (int kk = 0; kk < 8; ++kk) {
            const float* p = Sigma + (colg + n * 16) * NY + kk * 32 + ksub;
            float4 lo = *reinterpret_cast<const float4*>(p);
            float4 hi = *reinterpret_cast<const float4*>(p + 4);
            f16x8 bv;
            bv[0] = (_Float16)lo.x; bv[1] = (_Float16)lo.y;
            bv[2] = (_Float16)lo.z; bv[3] = (_Float16)lo.w;
            bv[4] = (_Float16)hi.x; bv[5] = (_Float16)hi.y;
            bv[6] = (_Float16)hi.z; bv[7] = (_Float16)hi.w;
            bfr[n][kk] = bv;
        }
    }

    // ---- preload st * yhat for the epilogue (lanes 0..15 only) ----
    float styh[4 * ROWS];
    if (lane < 16) {
#pragma unroll
        for (int r = 0; r < ROWS; ++r)
#pragma unroll
            for (int n = 0; n < 4; ++n)
                styh[r * 4 + n] = st * yhat[(r0 + r) * NY + w * 64 + n * 16 + lane];
    }

    f32x4 zz = {1.0f / 256.0f, 1.0f / 256.0f, 1.0f / 256.0f, 1.0f / 256.0f};
    float tk = 1.0f;
    float th = 0.0f;                      // warm-started simplex threshold
    __syncthreads();

    for (int it = 0; it < NIT; ++it) {
        // ---- grad phase: acc[n] = (Zy @ Sigma) tile (16x16), K=256 ----
        f32x4 acc[4] = {{0,0,0,0},{0,0,0,0},{0,0,0,0},{0,0,0,0}};
        const int arow  = lane & 15;
        const int abase = arow * 512;
        const int aswz  = (arow & 7) << 4;
#pragma unroll
        for (int kk = 0; kk < 8; ++kk) {
            const int aoff = (kk * 64 + (lane >> 4) * 16) ^ aswz;
            f16x8 af = *reinterpret_cast<const f16x8*>(
                reinterpret_cast<const char*>(zyA) + abase + aoff);
#pragma unroll
            for (int n = 0; n < 4; ++n)
                acc[n] = __builtin_amdgcn_mfma_f32_16x16x32_f16(af, bfr[n][kk],
                                                                acc[n], 0, 0, 0);
        }
        // ---- epilogue: v = zy - st*(2g - yhat); lanes 0..15 hold rows ----
        if (lane < 16) {
#pragma unroll
            for (int r = 0; r < ROWS; ++r) {
#pragma unroll
                for (int n = 0; n < 4; ++n) {
                    const int c = w * 64 + n * 16 + lane;
                    float zyo = vbuf[r * 256 + c];
                    vbuf[r * 256 + c] = zyo - st2 * acc[n][r] + styh[r * 4 + n];
                }
            }
        }
        __syncthreads();

        // ---- projection: wave w projects row prow onto the simplex ----
        f32x4 v4 = *reinterpret_cast<const f32x4*>(vbuf + prow * 256 + lane * 4);
        const float ps  = dpp_sum64(v4[0] + v4[1] + v4[2] + v4[3]);
        const float th0 = (ps - 1.0f) * (1.0f / 256.0f);   // always <= theta*

        for (int nit = 0; nit < 16; ++nit) {
            float d0 = v4[0] - th, d1 = v4[1] - th;
            float d2 = v4[2] - th, d3 = v4[3] - th;
            float sp = fmaxf(d0, 0.f) + fmaxf(d1, 0.f) +
                       fmaxf(d2, 0.f) + fmaxf(d3, 0.f);
            float s_tot = dpp_sum64(sp);                    // uniform (SGPR)
            int ci = __popcll(__ballot(d0 > 0.f)) + __popcll(__ballot(d1 > 0.f)) +
                     __popcll(__ballot(d2 > 0.f)) + __popcll(__ballot(d3 > 0.f));
            if (ci == 0) { th = th0; continue; }            // overshot: restart low
            if (fabsf(s_tot - 1.0f) <= 1e-6f) break;        // converged
            th += (s_tot - 1.0f) / (float)ci;               // Newton step
        }

        f32x4 zn;
        zn[0] = fmaxf(v4[0] - th, 0.f);
        zn[1] = fmaxf(v4[1] - th, 0.f);
        zn[2] = fmaxf(v4[2] - th, 0.f);
        zn[3] = fmaxf(v4[3] - th, 0.f);

        const float tn   = 0.5f * (1.0f + sqrtf(1.0f + 4.0f * tk * tk));
        const float beta = (tk - 1.0f) / tn;
        tk = tn;
        f32x4 zyn;
        zyn[0] = zn[0] + beta * (zn[0] - zz[0]);
        zyn[1] = zn[1] + beta * (zn[1] - zz[1]);
        zyn[2] = zn[2] + beta * (zn[2] - zz[2]);
        zyn[3] = zn[3] + beta * (zn[3] - zz[3]);
        zz = zn;

        // write zyn: fp32 -> vbuf, f16 -> zyA (swizzled row prow)
        // waves with the same prow write identical bits (benign race)
        *reinterpret_cast<f32x4*>(vbuf + prow * 256 + lane * 4) = zyn;
        {
            const int off = (lane * 8) ^ ((prow & 7) << 4);
            f16x4 hz;
            hz[0] = (_Float16)zyn[0]; hz[1] = (_Float16)zyn[1];
            hz[2] = (_Float16)zyn[2]; hz[3] = (_Float16)zyn[3];
            *reinterpret_cast<f16x4*>(
                reinterpret_cast<char*>(zyA) + prow * 512 + off) = hz;
        }
        __syncthreads();
    }

    // ---- output: waves 0..ROWS-1 write their rows ----
    if (w < ROWS)
        *reinterpret_cast<f32x4*>(zout + (r0 + w) * NY + lane * 4) = zz;
}

// ---------------------------------------------------------------------------
extern "C" void kernel_launch(void* const* d_in, const int* in_sizes, int n_in,
                              void* d_out, int out_size, void* d_ws, size_t ws_size,
                              hipStream_t stream) {
    const float* X = (const float*)d_in[0];
    const float* Y = (const float*)d_in[1];
    const float* W = (const float*)d_in[2];
    const float* b = (const float*)d_in[3];

    float* z_out = (float*)d_out;            // (1024, 256)
    float* yhat  = z_out + NOBS * NY;        // (1024, 256) -- second output

    float* ws    = (float*)d_ws;
    float* mu    = ws;                       // 256
    float* Sigma = ws + NY;                  // 65536
    float* stepv = ws + NY + NY * NY;        // 1

    yhat_kernel<<<NOBS, 256, 0, stream>>>(X, W, b, yhat);
    mu_kernel<<<NY, 256, 0, stream>>>(Y, yhat, mu);
    sigma_kernel<<<NY, 256, 0, stream>>>(Y, yhat, mu, Sigma);
    step_kernel<<<1, 1024, 0, stream>>>(Sigma, stepv);
    fista_mfma_kernel<<<NBLK, 256, 0, stream>>>(Sigma, yhat, stepv, z_out);
}